// Round 6
// baseline (123.273 us; speedup 1.0000x reference)
//
#include <hip/hip_runtime.h>
#include <hip/hip_fp16.h>

// Problem constants (from reference): B,R,P,C,H,W = 4,4096,64,32,256,256
constexpr int TB = 4, TR = 4096, TP = 64, TC = 32, TH = 256, TW = 256;
constexpr long long HW = (long long)TH * TW;                    // 65536
constexpr long long NPTS = (long long)TB * TR * TP;             // 1,048,576
constexpr long long FEATS_ELEMS = NPTS * TC;                    // 33,554,432
constexpr long long TRANS_ELEMS = (long long)TB * 3 * TC * HW;  // 25,165,824
constexpr unsigned PLANE_ELEMS = (unsigned)(HW * TC);           // 2,097,152 halves

typedef float fvec4 __attribute__((ext_vector_type(4)));
typedef unsigned uvec4 __attribute__((ext_vector_type(4)));

// ---------------------------------------------------------------------------
// Transpose+downconvert features [B,3,C,H,W] f32 -> [B,3,H,W,C] fp16.
// ---------------------------------------------------------------------------
__global__ __launch_bounds__(256) void transpose_feats(
    const float* __restrict__ in, __half* __restrict__ out) {
  __shared__ float tile[32][33];
  const int x0 = blockIdx.x * 32;
  const int y  = blockIdx.y;
  const int pk = blockIdx.z;
  const float* pin  = in  + (long long)pk * TC * HW;
  __half*      pout = out + (long long)pk * HW * TC;
  const int tx = threadIdx.x, ty = threadIdx.y;
  const int t = ty * 32 + tx;
#pragma unroll
  for (int i = 0; i < 4; ++i) {
    int c = ty + i * 8;
    tile[c][tx] = __builtin_nontemporal_load(
        pin + (long long)c * HW + (long long)y * TW + x0 + tx);
  }
  __syncthreads();
#pragma unroll
  for (int i = 0; i < 2; ++i) {
    int pair = t + i * 256;
    int x  = pair >> 4;
    int c2 = pair & 15;
    float2 f = make_float2(tile[2 * c2][x], tile[2 * c2 + 1][x]);
    __half2 h = __float22half2_rn(f);
    unsigned int bits;
    __builtin_memcpy(&bits, &h, 4);
    __builtin_nontemporal_store(
        bits, (unsigned int*)(pout + ((long long)y * TW + x0 + x) * TC + 2 * c2));
  }
}

// ---------------------------------------------------------------------------
// Per-ray prologue: world->local transform once per ray (B*R = 16384 rays).
// ---------------------------------------------------------------------------
__global__ __launch_bounds__(256) void rays_kernel(
    const float* __restrict__ o, const float* __restrict__ d,
    const float* __restrict__ w2l, float* __restrict__ rays) {
  int i = blockIdx.x * 256 + threadIdx.x;
  if (i >= TB * TR) return;
  int b = i >> 12;  // TR = 4096
  const float* M = w2l + b * 16;
  float ox = o[i * 3], oy = o[i * 3 + 1], oz = o[i * 3 + 2];
  float dx = d[i * 3], dy = d[i * 3 + 1], dz = d[i * 3 + 2];
  fvec4 ol = {ox * M[0] + oy * M[4] + oz * M[8]  + M[12],
              ox * M[1] + oy * M[5] + oz * M[9]  + M[13],
              ox * M[2] + oy * M[6] + oz * M[10] + M[14], 0.f};
  fvec4 dl = {dx * M[0] + dy * M[4] + dz * M[8],
              dx * M[1] + dy * M[5] + dz * M[9],
              dx * M[2] + dy * M[6] + dz * M[10], 0.f};
  ((fvec4*)rays)[i * 2]     = ol;
  ((fvec4*)rays)[i * 2 + 1] = dl;
}

// ---------------------------------------------------------------------------
// Tap prep: offsets (half-element units, channel base folded) + folded weights.
// ---------------------------------------------------------------------------
__device__ __forceinline__ void prep_plane(float x, float y, unsigned ebase,
                                           unsigned* offs, float* w) {
  float fx = fmaf(x, 128.f, 127.5f);
  float fy = fmaf(y, 128.f, 127.5f);
  float x0f = floorf(fx), y0f = floorf(fy);
  float wx = fx - x0f, wy = fy - y0f;
  int x0 = (int)x0f, y0 = (int)y0f;
  int x1 = x0 + 1, y1 = y0 + 1;
  float vx0 = (x0 >= 0 && x0 < TW) ? 1.f : 0.f;
  float vx1 = (x1 >= 0 && x1 < TW) ? 1.f : 0.f;
  float vy0 = (y0 >= 0 && y0 < TH) ? 1.f : 0.f;
  float vy1 = (y1 >= 0 && y1 < TH) ? 1.f : 0.f;
  unsigned cx0 = (unsigned)min(max(x0, 0), TW - 1);
  unsigned cx1 = (unsigned)min(max(x1, 0), TW - 1);
  unsigned cy0 = (unsigned)min(max(y0, 0), TH - 1);
  unsigned cy1 = (unsigned)min(max(y1, 0), TH - 1);
  w[0] = (1.f - wx) * (1.f - wy) * vx0 * vy0;
  w[1] = wx * (1.f - wy) * vx1 * vy0;
  w[2] = (1.f - wx) * wy * vx0 * vy1;
  w[3] = wx * wy * vx1 * vy1;
  unsigned r0 = ebase + (cy0 << 13), r1 = ebase + (cy1 << 13);
  offs[0] = r0 + (cx0 << 5);
  offs[1] = r0 + (cx1 << 5);
  offs[2] = r1 + (cx0 << 5);
  offs[3] = r1 + (cx1 << 5);
}

__device__ __forceinline__ void consume12(const uvec4* v, const float* w,
                                          float* acc) {
#pragma unroll
  for (int i = 0; i < 12; ++i) {
#pragma unroll
    for (int j = 0; j < 4; ++j) {
      unsigned bits = v[i][j];
      __half2 h;
      __builtin_memcpy(&h, &bits, 4);
      float2 f = __half22float2(h);
      acc[2 * j]     = fmaf(w[i], f.x, acc[2 * j]);
      acc[2 * j + 1] = fmaf(w[i], f.y, acc[2 * j + 1]);
    }
  }
}

// ---------------------------------------------------------------------------
// Sampler: block = 2 rays (128 points), thread = 2 points x (c8 quad-lane).
// 24 dwordx4 gathers issued before any consumption -> 2x MLP vs R5.
// ---------------------------------------------------------------------------
__global__ __launch_bounds__(256, 2) void sample_fast(
    const float* __restrict__ lengths, const float* __restrict__ rays,
    const __half* __restrict__ T, float* __restrict__ out) {
  const int blk = blockIdx.x;
  const int br0 = blk * 2, br1 = br0 + 1;   // two rays, same batch b
  const int b   = br0 >> 12;                // TR = 4096
  const fvec4 ol0 = ((const fvec4*)rays)[br0 * 2];
  const fvec4 dl0 = ((const fvec4*)rays)[br0 * 2 + 1];
  const fvec4 ol1 = ((const fvec4*)rays)[br1 * 2];
  const fvec4 dl1 = ((const fvec4*)rays)[br1 * 2 + 1];
  const int tid = threadIdx.x;
  const int p   = tid >> 2;            // point 0..63 (in each ray)
  const int c8  = (tid & 3) << 3;      // channel octet base
  const float t0 = lengths[(long long)br0 * TP + p];
  const float t1 = lengths[(long long)br1 * TP + p];
  const float px0 = fmaf(dl0.x, t0, ol0.x);
  const float py0 = fmaf(dl0.y, t0, ol0.y);
  const float pz0 = fmaf(dl0.z, t0, ol0.z);
  const float px1 = fmaf(dl1.x, t1, ol1.x);
  const float py1 = fmaf(dl1.y, t1, ol1.y);
  const float pz1 = fmaf(dl1.z, t1, ol1.z);

  unsigned offs0[12], offs1[12];
  float w0[12], w1[12];
  prep_plane(px0, py0, (unsigned)c8,                   offs0 + 0, w0 + 0);
  prep_plane(px0, pz0, (unsigned)c8 + PLANE_ELEMS,     offs0 + 4, w0 + 4);
  prep_plane(py0, pz0, (unsigned)c8 + 2 * PLANE_ELEMS, offs0 + 8, w0 + 8);
  prep_plane(px1, py1, (unsigned)c8,                   offs1 + 0, w1 + 0);
  prep_plane(px1, pz1, (unsigned)c8 + PLANE_ELEMS,     offs1 + 4, w1 + 4);
  prep_plane(py1, pz1, (unsigned)c8 + 2 * PLANE_ELEMS, offs1 + 8, w1 + 8);

  const __half* Tb = T + (size_t)b * (3 * (size_t)PLANE_ELEMS);
  uvec4 v0[12], v1[12];
#pragma unroll
  for (int i = 0; i < 12; ++i)
    v0[i] = *(const uvec4*)(Tb + offs0[i]);
#pragma unroll
  for (int i = 0; i < 12; ++i)
    v1[i] = *(const uvec4*)(Tb + offs1[i]);
  // Pin: all 24 gathers issued before any unpack/FMA consumes them.
  __builtin_amdgcn_sched_barrier(0);

  float acc0[8] = {0.f}, acc1[8] = {0.f};
  consume12(v0, w0, acc0);
  const long long point0 = (long long)br0 * 64 + p;
  {
    fvec4 oA = {acc0[0], acc0[1], acc0[2], acc0[3]};
    fvec4 oB = {acc0[4], acc0[5], acc0[6], acc0[7]};
    float* outp = out + point0 * TC + c8;
    __builtin_nontemporal_store(oA, (fvec4*)outp);
    __builtin_nontemporal_store(oB, (fvec4*)(outp + 4));
  }
  consume12(v1, w1, acc1);
  const long long point1 = point0 + 64;
  {
    fvec4 oA = {acc1[0], acc1[1], acc1[2], acc1[3]};
    fvec4 oB = {acc1[4], acc1[5], acc1[6], acc1[7]};
    float* outp = out + point1 * TC + c8;
    __builtin_nontemporal_store(oA, (fvec4*)outp);
    __builtin_nontemporal_store(oB, (fvec4*)(outp + 4));
  }
  if (c8 == 0) {
    bool m0 = px0 >= -1.f && px0 <= 1.f && py0 >= -1.f && py0 <= 1.f &&
              pz0 >= -1.f && pz0 <= 1.f;
    bool m1 = px1 >= -1.f && px1 <= 1.f && py1 >= -1.f && py1 <= 1.f &&
              pz1 >= -1.f && pz1 <= 1.f;
    __builtin_nontemporal_store(m0 ? 1.f : 0.f, out + FEATS_ELEMS + point0);
    __builtin_nontemporal_store(m1 ? 1.f : 0.f, out + FEATS_ELEMS + point1);
  }
}

// ---------------------------------------------------------------------------
// Fallback (ws too small): sample directly from [C,H,W] f32. thread=(point,c).
// ---------------------------------------------------------------------------
__device__ __forceinline__ float bilin1(const float* __restrict__ plane,
                                        float x, float y) {
  float fx = fmaf(x, 128.f, 127.5f);
  float fy = fmaf(y, 128.f, 127.5f);
  float x0f = floorf(fx), y0f = floorf(fy);
  float wx = fx - x0f, wy = fy - y0f;
  int x0 = (int)x0f, y0 = (int)y0f;
  int x1 = x0 + 1, y1 = y0 + 1;
  float vx0 = (x0 >= 0 && x0 < TW) ? 1.f : 0.f;
  float vx1 = (x1 >= 0 && x1 < TW) ? 1.f : 0.f;
  float vy0 = (y0 >= 0 && y0 < TH) ? 1.f : 0.f;
  float vy1 = (y1 >= 0 && y1 < TH) ? 1.f : 0.f;
  int cx0 = min(max(x0, 0), TW - 1), cx1 = min(max(x1, 0), TW - 1);
  int cy0 = min(max(y0, 0), TH - 1), cy1 = min(max(y1, 0), TH - 1);
  float w00 = (1.f - wx) * (1.f - wy) * vx0 * vy0;
  float w10 = wx * (1.f - wy) * vx1 * vy0;
  float w01 = (1.f - wx) * wy * vx0 * vy1;
  float w11 = wx * wy * vx1 * vy1;
  return w00 * plane[(long long)cy0 * TW + cx0] +
         w10 * plane[(long long)cy0 * TW + cx1] +
         w01 * plane[(long long)cy1 * TW + cx0] +
         w11 * plane[(long long)cy1 * TW + cx1];
}

__global__ __launch_bounds__(256) void sample_direct(
    const float* __restrict__ origins, const float* __restrict__ directions,
    const float* __restrict__ lengths, const float* __restrict__ w2l,
    const float* __restrict__ feats, float* __restrict__ out) {
  long long idx = (long long)blockIdx.x * 256 + threadIdx.x;
  long long point = idx >> 5;
  int c = (int)idx & 31;
  int b = (int)(point / ((long long)TR * TP));
  int rp = (int)(point - (long long)b * TR * TP);
  int r = rp / TP;
  int p = rp - r * TP;
  const float* M = w2l + b * 16;
  long long br = (long long)b * TR + r;
  float ox = origins[br * 3 + 0], oy = origins[br * 3 + 1], oz = origins[br * 3 + 2];
  float dx = directions[br * 3 + 0], dy = directions[br * 3 + 1], dz = directions[br * 3 + 2];
  float t = lengths[br * TP + p];
  float olx = ox * M[0] + oy * M[4] + oz * M[8]  + M[12];
  float oly = ox * M[1] + oy * M[5] + oz * M[9]  + M[13];
  float olz = ox * M[2] + oy * M[6] + oz * M[10] + M[14];
  float dlx = dx * M[0] + dy * M[4] + dz * M[8];
  float dly = dx * M[1] + dy * M[5] + dz * M[9];
  float dlz = dx * M[2] + dy * M[6] + dz * M[10];
  float px = fmaf(dlx, t, olx);
  float py = fmaf(dly, t, oly);
  float pz = fmaf(dlz, t, olz);
  const float* base = feats + (long long)b * 3 * TC * HW + (long long)c * HW;
  float v = bilin1(base, px, py);
  v += bilin1(base + (long long)TC * HW, px, pz);
  v += bilin1(base + 2ll * TC * HW, py, pz);
  out[point * TC + c] = v;
  if (c == 0) {
    bool m = px >= -1.f && px <= 1.f && py >= -1.f && py <= 1.f &&
             pz >= -1.f && pz <= 1.f;
    out[FEATS_ELEMS + point] = m ? 1.f : 0.f;
  }
}

extern "C" void kernel_launch(void* const* d_in, const int* in_sizes, int n_in,
                              void* d_out, int out_size, void* d_ws, size_t ws_size,
                              hipStream_t stream) {
  const float* origins    = (const float*)d_in[0];
  const float* directions = (const float*)d_in[1];
  const float* lengths    = (const float*)d_in[2];
  const float* features   = (const float*)d_in[3];
  const float* w2l        = (const float*)d_in[4];
  float* out = (float*)d_out;

  const size_t table_bytes = (size_t)TRANS_ELEMS * sizeof(__half);   // 50.3 MB
  const size_t rays_bytes  = (size_t)TB * TR * 8 * sizeof(float);    // 512 KB
  if (ws_size >= table_bytes + rays_bytes) {
    __half* T  = (__half*)d_ws;
    float* rays = (float*)((char*)d_ws + table_bytes);
    dim3 tg(TW / 32, TH, TB * 3), tb(32, 8);
    transpose_feats<<<tg, tb, 0, stream>>>(features, T);
    rays_kernel<<<(TB * TR + 255) / 256, 256, 0, stream>>>(
        origins, directions, w2l, rays);
    sample_fast<<<TB * TR / 2, 256, 0, stream>>>(lengths, rays, T, out);
  } else {
    long long total = NPTS * 32;
    sample_direct<<<(int)(total / 256), 256, 0, stream>>>(
        origins, directions, lengths, w2l, features, out);
  }
}